// Round 9
// baseline (245.282 us; speedup 1.0000x reference)
//
#include <hip/hip_runtime.h>
#include <hip/hip_bf16.h>

typedef __bf16 bf16x2 __attribute__((ext_vector_type(2)));
typedef __bf16 bf16x4 __attribute__((ext_vector_type(4)));
typedef __bf16 bf16x8 __attribute__((ext_vector_type(8)));
typedef float  f32x4  __attribute__((ext_vector_type(4)));

#define SEQ    2048
#define EMB    512
#define NHEAD  8
#define HD     64
#define NBATCH 4
#define MROWS  (NBATCH*SEQ)   /* 8192 */
// 0.125 * log2(e): folds head-dim scale + exp->exp2 conversion into Q
#define QSCALE 0.18033688011112042f
#define INV2PI 0.15915494309189535f
#define TWOPI  6.28318530717958648f
#define NEGFREQ (-0.41524101186092028f)   /* -log2(10000)/32 */

__device__ __forceinline__ f32x4 mfma16(bf16x8 a, bf16x8 b, f32x4 c) {
  return __builtin_amdgcn_mfma_f32_16x16x32_bf16(a, b, c, 0, 0, 0);
}

typedef __attribute__((address_space(1))) const void gv_t;
typedef __attribute__((address_space(3))) void lv_t;
__device__ __forceinline__ void async16(const void* g, void* l) {
  __builtin_amdgcn_global_load_lds((gv_t*)g, (lv_t*)l, 16, 0, 0);
}

// ---------------------------------------------------------------------------
// fp32 -> bf16 conversion: Q/K/V inputs (z=0..2), weights (z=3, 512 blocks),
// and xPos sin/cos table precompute (z=4, 256 blocks). [R7-verified]
// ---------------------------------------------------------------------------
__global__ __launch_bounds__(256) void conv_kernel(const float* __restrict__ q,
                                                   const float* __restrict__ k,
                                                   const float* __restrict__ v,
                                                   const float* __restrict__ wq,
                                                   const float* __restrict__ wk,
                                                   const float* __restrict__ wv,
                                                   const float* __restrict__ wo,
                                                   __bf16* __restrict__ Qf,
                                                   __bf16* __restrict__ Kf,
                                                   __bf16* __restrict__ Vf,
                                                   __bf16* __restrict__ Wb,
                                                   float2* __restrict__ qtab,
                                                   float2* __restrict__ ktab) {
  const int z = blockIdx.y;
  if (z == 4) {
    if (blockIdx.x >= 256) return;
    const int t = threadIdx.x;
    const int l = blockIdx.x * 8 + (t >> 5);     // row 0..2047
    const int i = t & 31;                        // dim pair 0..31
    const float lf = (float)l;
    const float pw = (lf - 1024.0f) * (1.0f / 512.0f);
    const float lb = __log2f((2.0f * i + 25.6f) * (1.0f / 89.6f));
    const float sc_q = __builtin_amdgcn_exp2f(pw * lb) * QSCALE;
    const float sc_k = __builtin_amdgcn_exp2f(-pw * lb);
    const float ang = lf * __builtin_amdgcn_exp2f((float)i * NEGFREQ);
    float rev = ang * INV2PI;
    rev -= floorf(rev);
    const float ar = rev * TWOPI;
    const float sn = __sinf(ar);
    const float cs = __cosf(ar);
    qtab[l * 32 + i] = float2{ cs * sc_q, sn * sc_q };
    ktab[l * 32 + i] = float2{ cs * sc_k, sn * sc_k };
    return;
  }
  const float* src;
  __bf16* dst;
  size_t i8;
  if (z < 3) {
    src = (z == 0) ? q : (z == 1) ? k : v;
    dst = (z == 0) ? Qf : (z == 1) ? Kf : Vf;
    i8 = ((size_t)blockIdx.x * 256 + threadIdx.x) * 8;
  } else {
    if (blockIdx.x >= 512) return;
    const int zw = blockIdx.x >> 7;                 // 0..3
    src = (zw == 0) ? wq : (zw == 1) ? wk : (zw == 2) ? wv : wo;
    dst = Wb + (size_t)zw * (EMB * EMB);
    i8 = ((size_t)(blockIdx.x & 127) * 256 + threadIdx.x) * 8;
  }
  const float4 fa = ((const float4*)(src + i8))[0];
  const float4 fb = ((const float4*)(src + i8))[1];
  bf16x8 h = { (__bf16)fa.x, (__bf16)fa.y, (__bf16)fa.z, (__bf16)fa.w,
               (__bf16)fb.x, (__bf16)fb.y, (__bf16)fb.z, (__bf16)fb.w };
  *(bf16x8*)(dst + i8) = h;
}

// ---------------------------------------------------------------------------
// Shared GEMM mainloop: C128x128 = A[M,512] @ W[N,512]^T, BOTH operands bf16
// staged via swizzled async16 (16 KB each, stride-64 xor layout). [R4-verified]
// ---------------------------------------------------------------------------
__device__ __forceinline__ void gemm_main(const __bf16* __restrict__ A,
                                          const __bf16* __restrict__ W,
                                          __bf16* As, __bf16* Bs,
                                          f32x4 (&acc)[4][4], int m0, int n0) {
  const int tid = threadIdx.x;
  const int wid = tid >> 6, lane = tid & 63;
  const int quad = lane >> 4, l16 = lane & 15;
  const int l7 = l16 & 7;
  const int srow = lane >> 3;
  const int sxor = ((lane & 7) ^ srow) * 8;     // swizzled source column (halves)
  const int wm = (wid >> 1) * 64, wn = (wid & 1) * 64;

  #pragma unroll
  for (int i = 0; i < 4; ++i)
    #pragma unroll
    for (int j = 0; j < 4; ++j) acc[i][j] = (f32x4)(0.0f);

  for (int k0 = 0; k0 < 512; k0 += 64) {
    __syncthreads();
    #pragma unroll
    for (int ii = 0; ii < 4; ++ii) {
      const int r8 = wid * 32 + ii * 8;
      async16(A + (size_t)(m0 + r8 + srow) * 512 + k0 + sxor, &As[r8 * 64]);
      async16(W + (size_t)(n0 + r8 + srow) * 512 + k0 + sxor, &Bs[r8 * 64]);
    }
    __syncthreads();
    #pragma unroll
    for (int ks = 0; ks < 2; ++ks) {
      bf16x8 af[4], bfr[4];
      #pragma unroll
      for (int i = 0; i < 4; ++i)
        af[i] = *(const bf16x8*)&As[(wm + i * 16 + l16) * 64 +
                                    (((quad + ks * 4) ^ l7) * 8)];
      #pragma unroll
      for (int j = 0; j < 4; ++j)
        bfr[j] = *(const bf16x8*)&Bs[(wn + j * 16 + l16) * 64 +
                                     (((quad + ks * 4) ^ l7) * 8)];
      #pragma unroll
      for (int i = 0; i < 4; ++i)
        #pragma unroll
        for (int j = 0; j < 4; ++j)
          acc[i][j] = mfma16(af[i], bfr[j], acc[i][j]);
    }
  }
}

// XCD-locality swizzle for the (4 n) x (64 m) GEMM grids.
__device__ __forceinline__ void xcd_tile(int& m0, int& n0) {
  const int s = blockIdx.y * 4 + blockIdx.x;    // dispatch slot within z
  const int t = s >> 3;
  n0 = (t & 3) * 128;
  m0 = ((s & 7) + ((t >> 2) << 3)) * 128;
}

// ---------------------------------------------------------------------------
// Projection GEMM with fused epilogues. [R7-verified]
// ---------------------------------------------------------------------------
__global__ __launch_bounds__(256) void gemm_proj_kernel(
    const __bf16* __restrict__ Qf, const __bf16* __restrict__ Kf, const __bf16* __restrict__ Vf,
    const __bf16* __restrict__ Wb,
    const float* __restrict__ bq, const float* __restrict__ bk, const float* __restrict__ bv,
    const float2* __restrict__ qtab, const float2* __restrict__ ktab,
    __bf16* __restrict__ Qx, __bf16* __restrict__ Kx, __bf16* __restrict__ Vt) {
  __shared__ __align__(16) char smem[34816];
  __bf16* As = (__bf16*)smem;
  __bf16* Bs = (__bf16*)(smem + 16384);
  __bf16* T  = (__bf16*)smem;                 // epilogue tile, stride 136 halves

  const int z = blockIdx.z;
  const __bf16* A = (z == 0) ? Qf : (z == 1) ? Kf : Vf;
  const __bf16* W = Wb + (size_t)z * (EMB * EMB);
  const float* bias = (z == 0) ? bq : (z == 1) ? bk : bv;
  int m0, n0;
  xcd_tile(m0, n0);

  f32x4 acc[4][4];
  gemm_main(A, W, As, Bs, acc, m0, n0);

  const int tid = threadIdx.x;
  const int wid = tid >> 6, lane = tid & 63;
  const int quad = lane >> 4, l16 = lane & 15;
  const int wm = (wid >> 1) * 64, wn = (wid & 1) * 64;

  __syncthreads();   // all waves done reading As/Bs before T overwrites them

  if (z == 2) {
    // transposed store [n][m] with vector writes (acc r-index runs along m)
    #pragma unroll
    for (int j = 0; j < 4; ++j) {
      const float bval = bias[n0 + wn + j * 16 + l16];
      #pragma unroll
      for (int i = 0; i < 4; ++i) {
        bf16x4 p = { (__bf16)(acc[i][j][0] + bval), (__bf16)(acc[i][j][1] + bval),
                     (__bf16)(acc[i][j][2] + bval), (__bf16)(acc[i][j][3] + bval) };
        *(bf16x4*)&T[(wn + j * 16 + l16) * 136 + wm + i * 16 + quad * 4] = p;
      }
    }
    __syncthreads();
    const int nrow = tid >> 1, mh = (tid & 1) << 6;
    bf16x8 vv[8];
    #pragma unroll
    for (int u = 0; u < 8; ++u) vv[u] = *(const bf16x8*)&T[nrow * 136 + mh + u * 8];
    const int n = n0 + nrow, h = n >> 6, d = n & 63;
    const int bb = m0 >> 11, lb2 = (m0 & 2047) + mh;
    __bf16* dst = Vt + ((size_t)(bb * 8 + h) * 64 + d) * 2048 + lb2;
    #pragma unroll
    for (int u = 0; u < 8; ++u) *(bf16x8*)(dst + u * 8) = vv[u];
  } else {
    // natural store [m][n] (scalar writes), then per-row xPos + coalesced out
    #pragma unroll
    for (int j = 0; j < 4; ++j) {
      const float bval = bias[n0 + wn + j * 16 + l16];
      #pragma unroll
      for (int i = 0; i < 4; ++i)
        #pragma unroll
        for (int r = 0; r < 4; ++r)
          T[(wm + i * 16 + quad * 4 + r) * 136 + wn + j * 16 + l16] =
              (__bf16)(acc[i][j][r] + bval);
    }
    __syncthreads();
    const int lrow = tid >> 1, half = tid & 1;
    const int gm = m0 + lrow, l = gm & 2047, bb = gm >> 11;
    const int h = (n0 >> 6) + half;
    bf16x8 vv[8];
    #pragma unroll
    for (int u = 0; u < 8; ++u)
      vv[u] = *(const bf16x8*)&T[lrow * 136 + half * 64 + u * 8];
    bf16x8 ov[8];
    // xPos rotation from the precomputed table: row l, pairs 0..31.
    const float4* trow = (const float4*)(((z == 0) ? qtab : ktab) + l * 32);
    #pragma unroll
    for (int p = 0; p < 16; ++p) {
      const float4 cs2 = trow[p];
      const int i0 = 2 * p;
      {
        const float x1 = (float)vv[i0 >> 2][(2 * i0) & 7];
        const float x2 = (float)vv[i0 >> 2][(2 * i0 + 1) & 7];
        ov[i0 >> 2][(2 * i0) & 7]     = (__bf16)(x1 * cs2.x - x2 * cs2.y);
        ov[i0 >> 2][(2 * i0 + 1) & 7] = (__bf16)(x2 * cs2.x + x1 * cs2.y);
      }
      {
        const int i1 = i0 + 1;
        const float x1 = (float)vv[i1 >> 2][(2 * i1) & 7];
        const float x2 = (float)vv[i1 >> 2][(2 * i1 + 1) & 7];
        ov[i1 >> 2][(2 * i1) & 7]     = (__bf16)(x1 * cs2.z - x2 * cs2.w);
        ov[i1 >> 2][(2 * i1 + 1) & 7] = (__bf16)(x2 * cs2.z + x1 * cs2.w);
      }
    }
    __bf16* dst = ((z == 0) ? Qx : Kx) + ((size_t)(bb * 8 + h) * 2048 + l) * 64;
    #pragma unroll
    for (int u = 0; u < 8; ++u) *(bf16x8*)(dst + u * 8) = ov[u];
  }
}

__global__ __launch_bounds__(256) void gemm_out_kernel(
    const __bf16* __restrict__ A, const __bf16* __restrict__ W,
    const float* __restrict__ bias, float* __restrict__ C) {
  __shared__ __align__(16) char smem[34816];
  __bf16* As = (__bf16*)smem;
  __bf16* Bs = (__bf16*)(smem + 16384);
  int m0, n0;
  xcd_tile(m0, n0);
  f32x4 acc[4][4];
  gemm_main(A, W, As, Bs, acc, m0, n0);
  const int tid = threadIdx.x;
  const int wid = tid >> 6, lane = tid & 63;
  const int quad = lane >> 4, l16 = lane & 15;
  const int wm = (wid >> 1) * 64, wn = (wid & 1) * 64;
  #pragma unroll
  for (int j = 0; j < 4; ++j) {
    const int n = n0 + wn + j * 16 + l16;
    const float bval = bias[n];
    #pragma unroll
    for (int i = 0; i < 4; ++i)
      #pragma unroll
      for (int r = 0; r < 4; ++r)
        C[(size_t)(m0 + wm + i * 16 + quad * 4 + r) * 512 + n] = acc[i][j][r] + bval;
  }
}

// ---------------------------------------------------------------------------
// Flash attention [R6-verified internals, 48.7us full-grid]: single-barrier
// dbuf K/V, P aliased into dead Qs, pointer-bump async16, compile-time buffer
// index, shared-zero acc init, per-lane defer check + deferred l-reduce,
// 1-dword mask pre-check. PROBE: launched as TWO half-head dispatches
// (hoff=0 and hoff=16, grid (16,32)) so each dispatch is ~25-28us -> the
// rocprof top-5 window reveals any other kernel above that threshold.
// ---------------------------------------------------------------------------
__global__ __launch_bounds__(256) void flash_kernel(const __bf16* __restrict__ Qx,
                                                    const __bf16* __restrict__ Kx,
                                                    const __bf16* __restrict__ Vt,
                                                    const unsigned char* __restrict__ kpm,
                                                    __bf16* __restrict__ Oa,
                                                    const int hoff) {
  __shared__ __align__(16) __bf16 Ks[2][64 * HD];
  __shared__ __align__(16) __bf16 Vs[2][64 * HD];
  __shared__ __align__(16) __bf16 Qs[64 * HD];   // per-wave P scratch after prologue

  const int tid = threadIdx.x;
  const int wid = tid >> 6;
  const int lane = tid & 63;
  const int quad = lane >> 4;
  const int l16 = lane & 15;
  const int l7 = l16 & 7;
  const int srow = lane >> 3;
  const int sxor = ((lane & 7) ^ srow) * 8;
  const int bh = (int)blockIdx.x + hoff;
  const int b = bh >> 3;
  const int qb = 31 - (int)blockIdx.y;        // longest-running blocks first
  const int q0 = qb * 64;

  const __bf16* Qbase = Qx + (size_t)bh * (SEQ * HD);
  const __bf16* Kbase = Kx + (size_t)bh * (SEQ * HD);
  const __bf16* Vbase = Vt + (size_t)bh * (HD * SEQ);
  // wave w reads only Q rows [16w,16w+16) == halves [1024w,1024w+1024):
  // exactly its private P region. No cross-wave hazard on the alias.
  __bf16* Pw = Qs + wid * 1024;

  // prologue: stage Q + K/V tile 0 (buffer 0), one barrier
  #pragma unroll
  for (int ii = 0; ii < 2; ++ii) {
    const int r0 = wid * 16 + ii * 8;
    async16(Qbase + (size_t)(q0 + r0 + srow) * HD + sxor, &Qs[r0 * HD]);
    async16(Kbase + (size_t)(r0 + srow) * HD + sxor, &Ks[0][r0 * HD]);
    async16(Vbase + (size_t)(r0 + srow) * SEQ + sxor, &Vs[0][r0 * HD]);
  }
  __syncthreads();

  // loop-invariant per-lane LDS element offsets (fold into ds immediates)
  const int base0 = (quad ^ l7) * 8;           // k-slice 0 column group
  const int base1 = ((quad + 4) ^ l7) * 8;     // k-slice 1 column group
  const int kvo0 = l16 * 64 + base0;           // K/V frag offset, ks=0
  const int kvo1 = l16 * 64 + base1;           // K/V frag offset, ks=1

  const bf16x8 qf0 = *(const bf16x8*)&Qs[(wid * 16 + l16) * HD + base0];
  const bf16x8 qf1 = *(const bf16x8*)&Qs[(wid * 16 + l16) * HD + base1];

  // P-store pointers (xor-swizzled 16B groups), loop-invariant
  __bf16* const pw0 = Pw + l16 * 64 + (((0 + (quad >> 1)) ^ l7) << 3) + (quad & 1) * 4;
  __bf16* const pw1 = Pw + l16 * 64 + (((2 + (quad >> 1)) ^ l7) << 3) + (quad & 1) * 4;
  __bf16* const pw2 = Pw + l16 * 64 + (((4 + (quad >> 1)) ^ l7) << 3) + (quad & 1) * 4;
  __bf16* const pw3 = Pw + l16 * 64 + (((6 + (quad >> 1)) ^ l7) << 3) + (quad & 1) * 4;
  const __bf16* const pr0 = Pw + kvo0;
  const __bf16* const pr1 = Pw + kvo1;

  f32x4 o[4];
  #pragma unroll
  for (int i = 0; i < 4; ++i) o[i] = (f32x4)(0.0f);
  const f32x4 z4 = (f32x4)(0.0f);              // shared zero C-operand
  float m_run = -1e30f, l_run = 0.0f;
  const int myq = q0 + wid * 16 + l16;
  const int niter = qb + 1;

  // next-tile (it=1) async16 source pointers; bumped by constants per prefetch
  const __bf16* kp0 = Kbase + (size_t)(64 + wid * 16 + srow) * HD + sxor;
  const __bf16* kp1 = kp0 + 8 * HD;
  const __bf16* vp0 = Vbase + (size_t)(wid * 16 + srow) * SEQ + 64 + sxor;
  const __bf16* vp1 = vp0 + 8 * SEQ;
  const unsigned char* kpmb = kpm + b * SEQ + (l16 << 2);

  int it = 0;

#define FLASH_STEP(CUR)                                                        \
  {                                                                            \
    const int kv0 = it << 6;                                                   \
    if (it + 1 < niter) {                                                      \
      async16(kp0, &Ks[1 - (CUR)][(wid * 16 + 0) * HD]);                       \
      async16(kp1, &Ks[1 - (CUR)][(wid * 16 + 8) * HD]);                       \
      async16(vp0, &Vs[1 - (CUR)][(wid * 16 + 0) * HD]);                       \
      async16(vp1, &Vs[1 - (CUR)][(wid * 16 + 8) * HD]);                       \
      kp0 += 64 * HD; kp1 += 64 * HD; vp0 += 64; vp1 += 64;                    \
    }                                                                          \
    const unsigned mine = *(const unsigned*)kpmb;                              \
    f32x4 s[4];                                                                \
    __builtin_amdgcn_s_setprio(1);                                             \
    s[0] = mfma16(*(const bf16x8*)&Ks[CUR][kvo0 +    0], qf0, z4);             \
    s[1] = mfma16(*(const bf16x8*)&Ks[CUR][kvo0 + 1024], qf0, z4);             \
    s[2] = mfma16(*(const bf16x8*)&Ks[CUR][kvo0 + 2048], qf0, z4);             \
    s[3] = mfma16(*(const bf16x8*)&Ks[CUR][kvo0 + 3072], qf0, z4);             \
    s[0] = mfma16(*(const bf16x8*)&Ks[CUR][kvo1 +    0], qf1, s[0]);           \
    s[1] = mfma16(*(const bf16x8*)&Ks[CUR][kvo1 + 1024], qf1, s[1]);           \
    s[2] = mfma16(*(const bf16x8*)&Ks[CUR][kvo1 + 2048], qf1, s[2]);           \
    s[3] = mfma16(*(const bf16x8*)&Ks[CUR][kvo1 + 3072], qf1, s[3]);           \
    __builtin_amdgcn_s_setprio(0);                                             \
    /* causal mask (diagonal tile only; wave-uniform branch) */                \
    if (kv0 + 63 > q0 + wid * 16) {                                            \
      _Pragma("unroll")                                                        \
      for (int nb = 0; nb < 4; ++nb)                                           \
        _Pragma("unroll")                                                      \
        for (int r = 0; r < 4; ++r)                                            \
          if (kv0 + nb * 16 + quad * 4 + r > myq) s[nb][r] = -1e30f;           \
    }                                                                          \
    /* key padding mask: rare path behind one-dword pre-check */               \
    if (__any(mine != 0)) {                                                    \
      const unsigned char* kq = kpm + b * SEQ + kv0;                           \
      _Pragma("unroll")                                                        \
      for (int nb = 0; nb < 4; ++nb) {                                         \
        const unsigned pk = *(const unsigned*)(kq + nb * 16 + quad * 4);       \
        if (pk) {                                                              \
          if (pk & 0x000000FFu) s[nb][0] = -1e30f;                             \
          if (pk & 0x0000FF00u) s[nb][1] = -1e30f;                             \
          if (pk & 0x00FF0000u) s[nb][2] = -1e30f;                             \
          if (pk & 0xFF000000u) s[nb][3] = -1e30f;                             \
        }                                                                      \
      }                                                                        \
    }                                                                          \
    /* online softmax, exp2 domain: per-lane max; cross-lane reduce + rescale  \
       only when some lane's max grew (exact, R2-verified) */                  \
    float mx;                                                                  \
    {                                                                          \
      f32x4 u0, u1;                                                            \
      _Pragma("unroll")                                                        \
      for (int r = 0; r < 4; ++r) u0[r] = fmaxf(s[0][r], s[1][r]);             \
      _Pragma("unroll")                                                        \
      for (int r = 0; r < 4; ++r) u1[r] = fmaxf(s[2][r], s[3][r]);             \
      _Pragma("unroll")                                                        \
      for (int r = 0; r < 4; ++r) u0[r] = fmaxf(u0[r], u1[r]);                 \
      mx = fmaxf(fmaxf(u0[0], u0[1]), fmaxf(u0[2], u0[3]));                    \
    }                                                                          \
    if (__any(mx > m_run)) {                                                   \
      float rm = fmaxf(mx, __shfl_xor(mx, 16));                                \
      rm = fmaxf(rm, __shfl_xor(rm, 32));                                      \
      const float m_new = fmaxf(m_run, rm);                                    \
      const float alpha = __builtin_amdgcn_exp2f(m_run - m_new);               \
      o[0] *= alpha; o[1] *= alpha; o[2] *= alpha; o[3] *= alpha;              \
      l_run *= alpha;                                                          \
      m_run = m_new;                                                           \
    }                                                                          \
    _Pragma("unroll")                                                          \
    for (int nb = 0; nb < 4; ++nb)                                             \
      _Pragma("unroll")                                                        \
      for (int r = 0; r < 4; ++r)                                              \
        s[nb][r] = __builtin_amdgcn_exp2f(s[nb][r] - m_run);                   \
    {                                                                          \
      f32x4 v01 = s[0] + s[1];                                                 \
      f32x4 v23 = s[2] + s[3];                                                 \
      f32x4 vt = v01 + v23;                                                    \
      l_run += (vt[0] + vt[1]) + (vt[2] + vt[3]);                              \
    }                                                                          \
    /* P transpose via wave-private LDS (no barrier; lgkmcnt-ordered) */       \
    *(bf16x4*)pw0 = bf16x4{ (__bf16)s[0][0], (__bf16)s[0][1],                  \
                            (__bf16)s[0][2], (__bf16)s[0][3] };                \
    *(bf16x4*)pw1 = bf16x4{ (__bf16)s[1][0], (__bf16)s[1][1],                  \
                            (__bf16)s[1][2], (__bf16)s[1][3] };                \
    *(bf16x4*)pw2 = bf16x4{ (__bf16)s[2][0], (__bf16)s[2][1],                  \
                            (__bf16)s[2][2], (__bf16)s[2][3] };                \
    *(bf16x4*)pw3 = bf16x4{ (__bf16)s[3][0], (__bf16)s[3][1],                  \
                            (__bf16)s[3][2], (__bf16)s[3][3] };                \
    /* O^T[d][q] += V^T(m=d) @ P^T(n=q=l16) */                                 \
    {                                                                          \
      const bf16x8 pf0 = *(const bf16x8*)pr0;                                  \
      __builtin_amdgcn_s_setprio(1);                                           \
      o[0] = mfma16(*(const bf16x8*)&Vs[CUR][kvo0 +    0], pf0, o[0]);         \
      o[1] = mfma16(*(const bf16x8*)&Vs[CUR][kvo0 + 1024], pf0, o[1]);         \
      o[2] = mfma16(*(const bf16x8*)&Vs[CUR][kvo0 + 2048], pf0, o[2]);         \
      o[3] = mfma16(*(const bf16x8*)&Vs[CUR][kvo0 + 3072], pf0, o[3]);         \
      __builtin_amdgcn_s_setprio(0);                                           \
      const bf16x8 pf1 = *(const bf16x8*)pr1;                                  \
      __builtin_amdgcn_s_setprio(1);                                           \
      o[0] = mfma16(*(const bf16x8*)&Vs[CUR][kvo1 +    0], pf1, o[0]);         \
      o[1] = mfma16(*(const bf16x8*)&Vs[CUR][kvo1 + 1024], pf1, o[1]);         \
      o[2] = mfma16(*(const bf16x8*)&Vs[CUR][kvo1 + 2048], pf1, o[2]);         \
      o[3] = mfma16(*(const bf16x8*)&Vs[CUR][kvo1 + 3072], pf1, o[3]);         \
      __builtin_amdgcn_s_setprio(0);                                           \
    }                                                                          \
    kpmb += 64;                                                                \
    /* single barrier per iteration: drains next-tile async16 (issued a full   \
       compute phase ago) + closes this tile's reads before next overwrite */  \
    if (it + 1 < niter) __syncthreads();                                       \
  }

  while (it + 1 < niter) {
    FLASH_STEP(0);
    ++it;
    FLASH_STEP(1);
    ++it;
  }
  if (it < niter) {
    FLASH_STEP(0);
  }
#undef FLASH_STEP

  // row-reduce l across the 4 quads sharing q=l16 (once per block)
  float lt = l_run + __shfl_xor(l_run, 16);
  lt += __shfl_xor(lt, 32);

  // epilogue: normalize, O^T -> (q,d) via per-wave LDS, coalesced store
  const float inv_l = 1.0f / lt;
  {
    bf16x4 t0 = { (__bf16)(o[0][0] * inv_l), (__bf16)(o[0][1] * inv_l),
                  (__bf16)(o[0][2] * inv_l), (__bf16)(o[0][3] * inv_l) };
    bf16x4 t1 = { (__bf16)(o[1][0] * inv_l), (__bf16)(o[1][1] * inv_l),
                  (__bf16)(o[1][2] * inv_l), (__bf16)(o[1][3] * inv_l) };
    bf16x4 t2 = { (__bf16)(o[2][0] * inv_l), (__bf16)(o[2][1] * inv_l),
                  (__bf16)(o[2][2] * inv_l), (__bf16)(o[2][3] * inv_l) };
    bf16x4 t3 = { (__bf16)(o[3][0] * inv_l), (__bf16)(o[3][1] * inv_l),
                  (__bf16)(o[3][2] * inv_l), (__bf16)(o[3][3] * inv_l) };
    *(bf16x4*)pw0 = t0;
    *(bf16x4*)pw1 = t1;
    *(bf16x4*)pw2 = t2;
    *(bf16x4*)pw3 = t3;
  }
  const int h = bh & 7;
  #pragma unroll
  for (int ii = 0; ii < 2; ++ii) {
    const int qr = ii * 8 + (lane >> 3);
    const bf16x8 ovv = *(const bf16x8*)&Pw[qr * 64 + (((lane & 7) ^ (qr & 7)) << 3)];
    *(bf16x8*)(Oa + (((size_t)b * SEQ + q0 + wid * 16 + qr) * NHEAD + h) * HD +
               (lane & 7) * 8) = ovv;
  }
}

// ---------------------------------------------------------------------------
extern "C" void kernel_launch(void* const* d_in, const int* in_sizes, int n_in,
                              void* d_out, int out_size, void* d_ws, size_t ws_size,
                              hipStream_t stream) {
  (void)in_sizes; (void)n_in; (void)out_size; (void)ws_size;
  const float* query = (const float*)d_in[0];
  const float* key   = (const float*)d_in[1];
  const float* value = (const float*)d_in[2];
  const unsigned char* kpm = (const unsigned char*)d_in[3];
  // d_in[4] = attn_mask: deterministic causal tril -> applied analytically
  const float* Wq = (const float*)d_in[5];
  const float* bq = (const float*)d_in[6];
  const float* Wk = (const float*)d_in[7];
  const float* bk = (const float*)d_in[8];
  const float* Wv = (const float*)d_in[9];
  const float* bv = (const float*)d_in[10];
  const float* Wo = (const float*)d_in[11];
  const float* bo = (const float*)d_in[12];
  float* out = (float*)d_out;

  char* ws = (char*)d_ws;
  const size_t SZ = (size_t)MROWS * EMB * 2;  // 8 MiB per bf16 tensor
  __bf16* Qf = (__bf16*)(ws);
  __bf16* Kf = (__bf16*)(ws + SZ);
  __bf16* Vf = (__bf16*)(ws + 2 * SZ);
  __bf16* Qx = (__bf16*)(ws + 3 * SZ);
  __bf16* Kx = (__bf16*)(ws + 4 * SZ);
  __bf16* Vt = (__bf16*)(ws + 5 * SZ);
  __bf16* Wb = (__bf16*)(ws + 6 * SZ);        // 4 x 512KB bf16 weights
  float2* qtab = (float2*)(ws + 6 * SZ + 4 * (size_t)(EMB * EMB) * 2);
  float2* ktab = qtab + SEQ * 32;             // 512KB each
  __bf16* Oa = Qf;                            // alias: Qf dead after proj GEMM

  conv_kernel<<<dim3(2048, 5), dim3(256), 0, stream>>>(
      query, key, value, Wq, Wk, Wv, Wo, Qf, Kf, Vf, Wb, qtab, ktab);
  gemm_proj_kernel<<<dim3(4, 64, 3), dim3(256), 0, stream>>>(
      Qf, Kf, Vf, Wb, bq, bk, bv, qtab, ktab, Qx, Kx, Vt);
  flash_kernel<<<dim3(16, 32), dim3(256), 0, stream>>>(Qx, Kx, Vt, kpm, Oa, 0);
  flash_kernel<<<dim3(16, 32), dim3(256), 0, stream>>>(Qx, Kx, Vt, kpm, Oa, 16);
  gemm_out_kernel<<<dim3(4, 64), dim3(256), 0, stream>>>(
      Oa, Wb + (size_t)3 * EMB * EMB, bo, out);
}

// Round 10
// 199.283 us; speedup vs baseline: 1.2308x; 1.2308x over previous
//
#include <hip/hip_runtime.h>
#include <hip/hip_bf16.h>

typedef __bf16 bf16x2 __attribute__((ext_vector_type(2)));
typedef __bf16 bf16x4 __attribute__((ext_vector_type(4)));
typedef __bf16 bf16x8 __attribute__((ext_vector_type(8)));
typedef float  f32x4  __attribute__((ext_vector_type(4)));

#define SEQ    2048
#define EMB    512
#define NHEAD  8
#define HD     64
#define NBATCH 4
#define MROWS  (NBATCH*SEQ)   /* 8192 */
// 0.125 * log2(e): folds head-dim scale + exp->exp2 conversion into Q
#define QSCALE 0.18033688011112042f
#define INV2PI 0.15915494309189535f
#define TWOPI  6.28318530717958648f
#define NEGFREQ (-0.41524101186092028f)   /* -log2(10000)/32 */

__device__ __forceinline__ f32x4 mfma16(bf16x8 a, bf16x8 b, f32x4 c) {
  return __builtin_amdgcn_mfma_f32_16x16x32_bf16(a, b, c, 0, 0, 0);
}

typedef __attribute__((address_space(1))) const void gv_t;
typedef __attribute__((address_space(3))) void lv_t;
__device__ __forceinline__ void async16(const void* g, void* l) {
  __builtin_amdgcn_global_load_lds((gv_t*)g, (lv_t*)l, 16, 0, 0);
}

// ---------------------------------------------------------------------------
// fp32 -> bf16 conversion: Q/K/V inputs (z=0..2), weights (z=3, 512 blocks),
// and xPos sin/cos table precompute (z=4, 256 blocks). [R7-verified]
// ---------------------------------------------------------------------------
__global__ __launch_bounds__(256) void conv_kernel(const float* __restrict__ q,
                                                   const float* __restrict__ k,
                                                   const float* __restrict__ v,
                                                   const float* __restrict__ wq,
                                                   const float* __restrict__ wk,
                                                   const float* __restrict__ wv,
                                                   const float* __restrict__ wo,
                                                   __bf16* __restrict__ Qf,
                                                   __bf16* __restrict__ Kf,
                                                   __bf16* __restrict__ Vf,
                                                   __bf16* __restrict__ Wb,
                                                   float2* __restrict__ qtab,
                                                   float2* __restrict__ ktab) {
  const int z = blockIdx.y;
  if (z == 4) {
    if (blockIdx.x >= 256) return;
    const int t = threadIdx.x;
    const int l = blockIdx.x * 8 + (t >> 5);     // row 0..2047
    const int i = t & 31;                        // dim pair 0..31
    const float lf = (float)l;
    const float pw = (lf - 1024.0f) * (1.0f / 512.0f);
    const float lb = __log2f((2.0f * i + 25.6f) * (1.0f / 89.6f));
    const float sc_q = __builtin_amdgcn_exp2f(pw * lb) * QSCALE;
    const float sc_k = __builtin_amdgcn_exp2f(-pw * lb);
    const float ang = lf * __builtin_amdgcn_exp2f((float)i * NEGFREQ);
    float rev = ang * INV2PI;
    rev -= floorf(rev);
    const float ar = rev * TWOPI;
    const float sn = __sinf(ar);
    const float cs = __cosf(ar);
    qtab[l * 32 + i] = float2{ cs * sc_q, sn * sc_q };
    ktab[l * 32 + i] = float2{ cs * sc_k, sn * sc_k };
    return;
  }
  const float* src;
  __bf16* dst;
  size_t i8;
  if (z < 3) {
    src = (z == 0) ? q : (z == 1) ? k : v;
    dst = (z == 0) ? Qf : (z == 1) ? Kf : Vf;
    i8 = ((size_t)blockIdx.x * 256 + threadIdx.x) * 8;
  } else {
    if (blockIdx.x >= 512) return;
    const int zw = blockIdx.x >> 7;                 // 0..3
    src = (zw == 0) ? wq : (zw == 1) ? wk : (zw == 2) ? wv : wo;
    dst = Wb + (size_t)zw * (EMB * EMB);
    i8 = ((size_t)(blockIdx.x & 127) * 256 + threadIdx.x) * 8;
  }
  const float4 fa = ((const float4*)(src + i8))[0];
  const float4 fb = ((const float4*)(src + i8))[1];
  bf16x8 h = { (__bf16)fa.x, (__bf16)fa.y, (__bf16)fa.z, (__bf16)fa.w,
               (__bf16)fb.x, (__bf16)fb.y, (__bf16)fb.z, (__bf16)fb.w };
  *(bf16x8*)(dst + i8) = h;
}

// ---------------------------------------------------------------------------
// Shared GEMM mainloop: C128x128 = A[M,512] @ W[N,512]^T, BOTH operands bf16
// staged via swizzled async16 (16 KB each, stride-64 xor layout). [R4-verified]
// ---------------------------------------------------------------------------
__device__ __forceinline__ void gemm_main(const __bf16* __restrict__ A,
                                          const __bf16* __restrict__ W,
                                          __bf16* As, __bf16* Bs,
                                          f32x4 (&acc)[4][4], int m0, int n0) {
  const int tid = threadIdx.x;
  const int wid = tid >> 6, lane = tid & 63;
  const int quad = lane >> 4, l16 = lane & 15;
  const int l7 = l16 & 7;
  const int srow = lane >> 3;
  const int sxor = ((lane & 7) ^ srow) * 8;     // swizzled source column (halves)
  const int wm = (wid >> 1) * 64, wn = (wid & 1) * 64;

  #pragma unroll
  for (int i = 0; i < 4; ++i)
    #pragma unroll
    for (int j = 0; j < 4; ++j) acc[i][j] = (f32x4)(0.0f);

  for (int k0 = 0; k0 < 512; k0 += 64) {
    __syncthreads();
    #pragma unroll
    for (int ii = 0; ii < 4; ++ii) {
      const int r8 = wid * 32 + ii * 8;
      async16(A + (size_t)(m0 + r8 + srow) * 512 + k0 + sxor, &As[r8 * 64]);
      async16(W + (size_t)(n0 + r8 + srow) * 512 + k0 + sxor, &Bs[r8 * 64]);
    }
    __syncthreads();
    #pragma unroll
    for (int ks = 0; ks < 2; ++ks) {
      bf16x8 af[4], bfr[4];
      #pragma unroll
      for (int i = 0; i < 4; ++i)
        af[i] = *(const bf16x8*)&As[(wm + i * 16 + l16) * 64 +
                                    (((quad + ks * 4) ^ l7) * 8)];
      #pragma unroll
      for (int j = 0; j < 4; ++j)
        bfr[j] = *(const bf16x8*)&Bs[(wn + j * 16 + l16) * 64 +
                                     (((quad + ks * 4) ^ l7) * 8)];
      #pragma unroll
      for (int i = 0; i < 4; ++i)
        #pragma unroll
        for (int j = 0; j < 4; ++j)
          acc[i][j] = mfma16(af[i], bfr[j], acc[i][j]);
    }
  }
}

// XCD-locality swizzle for the (4 n) x (64 m) GEMM grids.
__device__ __forceinline__ void xcd_tile(int& m0, int& n0) {
  const int s = blockIdx.y * 4 + blockIdx.x;    // dispatch slot within z
  const int t = s >> 3;
  n0 = (t & 3) * 128;
  m0 = ((s & 7) + ((t >> 2) << 3)) * 128;
}

// ---------------------------------------------------------------------------
// Projection GEMM with fused epilogues. [R7-verified]
// ---------------------------------------------------------------------------
__global__ __launch_bounds__(256) void gemm_proj_kernel(
    const __bf16* __restrict__ Qf, const __bf16* __restrict__ Kf, const __bf16* __restrict__ Vf,
    const __bf16* __restrict__ Wb,
    const float* __restrict__ bq, const float* __restrict__ bk, const float* __restrict__ bv,
    const float2* __restrict__ qtab, const float2* __restrict__ ktab,
    __bf16* __restrict__ Qx, __bf16* __restrict__ Kx, __bf16* __restrict__ Vt) {
  __shared__ __align__(16) char smem[34816];
  __bf16* As = (__bf16*)smem;
  __bf16* Bs = (__bf16*)(smem + 16384);
  __bf16* T  = (__bf16*)smem;                 // epilogue tile, stride 136 halves

  const int z = blockIdx.z;
  const __bf16* A = (z == 0) ? Qf : (z == 1) ? Kf : Vf;
  const __bf16* W = Wb + (size_t)z * (EMB * EMB);
  const float* bias = (z == 0) ? bq : (z == 1) ? bk : bv;
  int m0, n0;
  xcd_tile(m0, n0);

  f32x4 acc[4][4];
  gemm_main(A, W, As, Bs, acc, m0, n0);

  const int tid = threadIdx.x;
  const int wid = tid >> 6, lane = tid & 63;
  const int quad = lane >> 4, l16 = lane & 15;
  const int wm = (wid >> 1) * 64, wn = (wid & 1) * 64;

  __syncthreads();   // all waves done reading As/Bs before T overwrites them

  if (z == 2) {
    // transposed store [n][m] with vector writes (acc r-index runs along m)
    #pragma unroll
    for (int j = 0; j < 4; ++j) {
      const float bval = bias[n0 + wn + j * 16 + l16];
      #pragma unroll
      for (int i = 0; i < 4; ++i) {
        bf16x4 p = { (__bf16)(acc[i][j][0] + bval), (__bf16)(acc[i][j][1] + bval),
                     (__bf16)(acc[i][j][2] + bval), (__bf16)(acc[i][j][3] + bval) };
        *(bf16x4*)&T[(wn + j * 16 + l16) * 136 + wm + i * 16 + quad * 4] = p;
      }
    }
    __syncthreads();
    const int nrow = tid >> 1, mh = (tid & 1) << 6;
    bf16x8 vv[8];
    #pragma unroll
    for (int u = 0; u < 8; ++u) vv[u] = *(const bf16x8*)&T[nrow * 136 + mh + u * 8];
    const int n = n0 + nrow, h = n >> 6, d = n & 63;
    const int bb = m0 >> 11, lb2 = (m0 & 2047) + mh;
    __bf16* dst = Vt + ((size_t)(bb * 8 + h) * 64 + d) * 2048 + lb2;
    #pragma unroll
    for (int u = 0; u < 8; ++u) *(bf16x8*)(dst + u * 8) = vv[u];
  } else {
    // natural store [m][n] (scalar writes), then per-row xPos + coalesced out
    #pragma unroll
    for (int j = 0; j < 4; ++j) {
      const float bval = bias[n0 + wn + j * 16 + l16];
      #pragma unroll
      for (int i = 0; i < 4; ++i)
        #pragma unroll
        for (int r = 0; r < 4; ++r)
          T[(wm + i * 16 + quad * 4 + r) * 136 + wn + j * 16 + l16] =
              (__bf16)(acc[i][j][r] + bval);
    }
    __syncthreads();
    const int lrow = tid >> 1, half = tid & 1;
    const int gm = m0 + lrow, l = gm & 2047, bb = gm >> 11;
    const int h = (n0 >> 6) + half;
    bf16x8 vv[8];
    #pragma unroll
    for (int u = 0; u < 8; ++u)
      vv[u] = *(const bf16x8*)&T[lrow * 136 + half * 64 + u * 8];
    bf16x8 ov[8];
    // xPos rotation from the precomputed table: row l, pairs 0..31.
    const float4* trow = (const float4*)(((z == 0) ? qtab : ktab) + l * 32);
    #pragma unroll
    for (int p = 0; p < 16; ++p) {
      const float4 cs2 = trow[p];
      const int i0 = 2 * p;
      {
        const float x1 = (float)vv[i0 >> 2][(2 * i0) & 7];
        const float x2 = (float)vv[i0 >> 2][(2 * i0 + 1) & 7];
        ov[i0 >> 2][(2 * i0) & 7]     = (__bf16)(x1 * cs2.x - x2 * cs2.y);
        ov[i0 >> 2][(2 * i0 + 1) & 7] = (__bf16)(x2 * cs2.x + x1 * cs2.y);
      }
      {
        const int i1 = i0 + 1;
        const float x1 = (float)vv[i1 >> 2][(2 * i1) & 7];
        const float x2 = (float)vv[i1 >> 2][(2 * i1 + 1) & 7];
        ov[i1 >> 2][(2 * i1) & 7]     = (__bf16)(x1 * cs2.z - x2 * cs2.w);
        ov[i1 >> 2][(2 * i1 + 1) & 7] = (__bf16)(x2 * cs2.z + x1 * cs2.w);
      }
    }
    __bf16* dst = ((z == 0) ? Qx : Kx) + ((size_t)(bb * 8 + h) * 2048 + l) * 64;
    #pragma unroll
    for (int u = 0; u < 8; ++u) *(bf16x8*)(dst + u * 8) = ov[u];
  }
}

__global__ __launch_bounds__(256) void gemm_out_kernel(
    const __bf16* __restrict__ A, const __bf16* __restrict__ W,
    const float* __restrict__ bias, float* __restrict__ C) {
  __shared__ __align__(16) char smem[34816];
  __bf16* As = (__bf16*)smem;
  __bf16* Bs = (__bf16*)(smem + 16384);
  int m0, n0;
  xcd_tile(m0, n0);
  f32x4 acc[4][4];
  gemm_main(A, W, As, Bs, acc, m0, n0);
  const int tid = threadIdx.x;
  const int wid = tid >> 6, lane = tid & 63;
  const int quad = lane >> 4, l16 = lane & 15;
  const int wm = (wid >> 1) * 64, wn = (wid & 1) * 64;
  #pragma unroll
  for (int j = 0; j < 4; ++j) {
    const int n = n0 + wn + j * 16 + l16;
    const float bval = bias[n];
    #pragma unroll
    for (int i = 0; i < 4; ++i)
      #pragma unroll
      for (int r = 0; r < 4; ++r)
        C[(size_t)(m0 + wm + i * 16 + quad * 4 + r) * 512 + n] = acc[i][j][r] + bval;
  }
}

// ---------------------------------------------------------------------------
// Flash attention v8: KVBLK=128 (16-iteration chain, amortizes the measured
// ~1.2us fixed per-iter latency) at 40KB LDS via SINGLE-buffered K/V tiles
// (stage -> barrier -> compute, two barriers/iter; R0 measured that exposure
// as small). 4 blocks/CU, 1024 blocks = one scheduling round (R8's 2-round
// loss removed). Compute body identical to the R8-verified KVBLK=128 kernel.
// ---------------------------------------------------------------------------
__global__ __launch_bounds__(256) void flash_kernel(const __bf16* __restrict__ Qx,
                                                    const __bf16* __restrict__ Kx,
                                                    const __bf16* __restrict__ Vt,
                                                    const unsigned char* __restrict__ kpm,
                                                    __bf16* __restrict__ Oa) {
  __shared__ __align__(16) __bf16 Ks[2][64 * 64];  // [rowhalf][r*64+c] keys 0-63 / 64-127
  __shared__ __align__(16) __bf16 Vs[2][64 * 64];  // [colhalf][d*64+c]
  __shared__ __align__(16) __bf16 Qs[64 * HD];     // per-wave P scratch after prologue

  const int tid = threadIdx.x;
  const int wid = tid >> 6;
  const int lane = tid & 63;
  const int quad = lane >> 4;
  const int l16 = lane & 15;
  const int l7 = l16 & 7;
  const int srow = lane >> 3;
  const int sxor = ((lane & 7) ^ srow) * 8;
  const int bh = blockIdx.x;
  const int b = bh >> 3;
  const int qb = 31 - (int)blockIdx.y;        // longest-running blocks first
  const int q0 = qb * 64;

  const __bf16* Qbase = Qx + (size_t)bh * (SEQ * HD);
  const __bf16* Kbase = Kx + (size_t)bh * (SEQ * HD);
  const __bf16* Vbase = Vt + (size_t)bh * (HD * SEQ);
  __bf16* Pw = Qs + wid * 1024;               // wave-private P region (2KB)

  // staging pointers (tile 0 bases), bumped by constants per STAGE
  const __bf16* kp  = Kbase + (size_t)(wid * 32 + srow) * HD + sxor;
  const __bf16* vpA = Vbase + (size_t)(wid * 16 + srow) * SEQ + sxor;
  const __bf16* vpB = vpA + 8 * SEQ;

#define STAGE()                                                                \
  {                                                                            \
    async16(kp + 0 * 8 * HD, &Ks[wid >> 1][((wid & 1) * 32 +  0) * 64]);       \
    async16(kp + 1 * 8 * HD, &Ks[wid >> 1][((wid & 1) * 32 +  8) * 64]);       \
    async16(kp + 2 * 8 * HD, &Ks[wid >> 1][((wid & 1) * 32 + 16) * 64]);       \
    async16(kp + 3 * 8 * HD, &Ks[wid >> 1][((wid & 1) * 32 + 24) * 64]);       \
    async16(vpA +  0, &Vs[0][(wid * 16 + 0) * 64]);                            \
    async16(vpA + 64, &Vs[1][(wid * 16 + 0) * 64]);                            \
    async16(vpB +  0, &Vs[0][(wid * 16 + 8) * 64]);                            \
    async16(vpB + 64, &Vs[1][(wid * 16 + 8) * 64]);                            \
    kp += 128 * HD; vpA += 128; vpB += 128;                                    \
  }

  // prologue: stage Q + K/V tile 0, one barrier
  #pragma unroll
  for (int ii = 0; ii < 2; ++ii) {
    const int r0 = wid * 16 + ii * 8;
    async16(Qbase + (size_t)(q0 + r0 + srow) * HD + sxor, &Qs[r0 * HD]);
  }
  STAGE();
  __syncthreads();

  // loop-invariant per-lane LDS element offsets
  const int base0 = (quad ^ l7) * 8;           // k-slice 0 column group
  const int base1 = ((quad + 4) ^ l7) * 8;     // k-slice 1 column group
  const int kvo0 = l16 * 64 + base0;
  const int kvo1 = l16 * 64 + base1;

  const bf16x8 qf0 = *(const bf16x8*)&Qs[(wid * 16 + l16) * HD + base0];
  const bf16x8 qf1 = *(const bf16x8*)&Qs[(wid * 16 + l16) * HD + base1];

  // P-store pointers (xor-swizzled 16B groups), loop-invariant
  __bf16* const pw0 = Pw + l16 * 64 + (((0 + (quad >> 1)) ^ l7) << 3) + (quad & 1) * 4;
  __bf16* const pw1 = Pw + l16 * 64 + (((2 + (quad >> 1)) ^ l7) << 3) + (quad & 1) * 4;
  __bf16* const pw2 = Pw + l16 * 64 + (((4 + (quad >> 1)) ^ l7) << 3) + (quad & 1) * 4;
  __bf16* const pw3 = Pw + l16 * 64 + (((6 + (quad >> 1)) ^ l7) << 3) + (quad & 1) * 4;
  const __bf16* const pr0 = Pw + kvo0;
  const __bf16* const pr1 = Pw + kvo1;

  f32x4 o[4];
  #pragma unroll
  for (int i = 0; i < 4; ++i) o[i] = (f32x4)(0.0f);
  const f32x4 z4 = (f32x4)(0.0f);
  float m_run = -1e30f, l_run = 0.0f;
  const int myq = q0 + wid * 16 + l16;
  const int niter = (qb >> 1) + 1;            // 128-key tiles
  const unsigned char* kpmb = kpm + b * SEQ + (l16 << 3);

  for (int it = 0; it < niter; ++it) {
    const int kv0 = it << 7;
    const uint2 mine2 = *(const uint2*)kpmb;

    f32x4 s[8];
    __builtin_amdgcn_s_setprio(1);
    s[0] = mfma16(*(const bf16x8*)&Ks[0][kvo0 +    0], qf0, z4);
    s[1] = mfma16(*(const bf16x8*)&Ks[0][kvo0 + 1024], qf0, z4);
    s[2] = mfma16(*(const bf16x8*)&Ks[0][kvo0 + 2048], qf0, z4);
    s[3] = mfma16(*(const bf16x8*)&Ks[0][kvo0 + 3072], qf0, z4);
    s[4] = mfma16(*(const bf16x8*)&Ks[1][kvo0 +    0], qf0, z4);
    s[5] = mfma16(*(const bf16x8*)&Ks[1][kvo0 + 1024], qf0, z4);
    s[6] = mfma16(*(const bf16x8*)&Ks[1][kvo0 + 2048], qf0, z4);
    s[7] = mfma16(*(const bf16x8*)&Ks[1][kvo0 + 3072], qf0, z4);
    s[0] = mfma16(*(const bf16x8*)&Ks[0][kvo1 +    0], qf1, s[0]);
    s[1] = mfma16(*(const bf16x8*)&Ks[0][kvo1 + 1024], qf1, s[1]);
    s[2] = mfma16(*(const bf16x8*)&Ks[0][kvo1 + 2048], qf1, s[2]);
    s[3] = mfma16(*(const bf16x8*)&Ks[0][kvo1 + 3072], qf1, s[3]);
    s[4] = mfma16(*(const bf16x8*)&Ks[1][kvo1 +    0], qf1, s[4]);
    s[5] = mfma16(*(const bf16x8*)&Ks[1][kvo1 + 1024], qf1, s[5]);
    s[6] = mfma16(*(const bf16x8*)&Ks[1][kvo1 + 2048], qf1, s[6]);
    s[7] = mfma16(*(const bf16x8*)&Ks[1][kvo1 + 3072], qf1, s[7]);
    __builtin_amdgcn_s_setprio(0);

    // causal mask (tiles overlapping the diagonal; wave-uniform branch)
    if (kv0 + 127 > q0 + wid * 16) {
      #pragma unroll
      for (int nb = 0; nb < 8; ++nb)
        #pragma unroll
        for (int r = 0; r < 4; ++r)
          if (kv0 + nb * 16 + quad * 4 + r > myq) s[nb][r] = -1e30f;
    }
    // key padding mask: rare path behind one 8B pre-check
    if (__any((mine2.x | mine2.y) != 0)) {
      const unsigned char* kq = kpm + b * SEQ + kv0;
      #pragma unroll
      for (int nb = 0; nb < 8; ++nb) {
        const unsigned pk = *(const unsigned*)(kq + nb * 16 + quad * 4);
        if (pk) {
          if (pk & 0x000000FFu) s[nb][0] = -1e30f;
          if (pk & 0x0000FF00u) s[nb][1] = -1e30f;
          if (pk & 0x00FF0000u) s[nb][2] = -1e30f;
          if (pk & 0xFF000000u) s[nb][3] = -1e30f;
        }
      }
    }

    // online softmax over 32 vals/lane; cross-lane reduce only if max grew
    float mx;
    {
      f32x4 u0, u1, u2, u3;
      #pragma unroll
      for (int r = 0; r < 4; ++r) u0[r] = fmaxf(s[0][r], s[1][r]);
      #pragma unroll
      for (int r = 0; r < 4; ++r) u1[r] = fmaxf(s[2][r], s[3][r]);
      #pragma unroll
      for (int r = 0; r < 4; ++r) u2[r] = fmaxf(s[4][r], s[5][r]);
      #pragma unroll
      for (int r = 0; r < 4; ++r) u3[r] = fmaxf(s[6][r], s[7][r]);
      #pragma unroll
      for (int r = 0; r < 4; ++r) u0[r] = fmaxf(fmaxf(u0[r], u1[r]),
                                                fmaxf(u2[r], u3[r]));
      mx = fmaxf(fmaxf(u0[0], u0[1]), fmaxf(u0[2], u0[3]));
    }
    if (__any(mx > m_run)) {
      float rm = fmaxf(mx, __shfl_xor(mx, 16));
      rm = fmaxf(rm, __shfl_xor(rm, 32));
      const float m_new = fmaxf(m_run, rm);
      const float alpha = __builtin_amdgcn_exp2f(m_run - m_new);
      o[0] *= alpha; o[1] *= alpha; o[2] *= alpha; o[3] *= alpha;
      l_run *= alpha;
      m_run = m_new;
    }
    #pragma unroll
    for (int nb = 0; nb < 8; ++nb)
      #pragma unroll
      for (int r = 0; r < 4; ++r)
        s[nb][r] = __builtin_amdgcn_exp2f(s[nb][r] - m_run);
    {
      f32x4 va = (s[0] + s[1]) + (s[2] + s[3]);
      f32x4 vb = (s[4] + s[5]) + (s[6] + s[7]);
      f32x4 vt = va + vb;
      l_run += (vt[0] + vt[1]) + (vt[2] + vt[3]);
    }

    // PV half 0 (keys kv0..kv0+63): P from s[0..3] via wave-private LDS
    *(bf16x4*)pw0 = bf16x4{ (__bf16)s[0][0], (__bf16)s[0][1],
                            (__bf16)s[0][2], (__bf16)s[0][3] };
    *(bf16x4*)pw1 = bf16x4{ (__bf16)s[1][0], (__bf16)s[1][1],
                            (__bf16)s[1][2], (__bf16)s[1][3] };
    *(bf16x4*)pw2 = bf16x4{ (__bf16)s[2][0], (__bf16)s[2][1],
                            (__bf16)s[2][2], (__bf16)s[2][3] };
    *(bf16x4*)pw3 = bf16x4{ (__bf16)s[3][0], (__bf16)s[3][1],
                            (__bf16)s[3][2], (__bf16)s[3][3] };
    {
      const bf16x8 pf0 = *(const bf16x8*)pr0;
      __builtin_amdgcn_s_setprio(1);
      o[0] = mfma16(*(const bf16x8*)&Vs[0][kvo0 +    0], pf0, o[0]);
      o[1] = mfma16(*(const bf16x8*)&Vs[0][kvo0 + 1024], pf0, o[1]);
      o[2] = mfma16(*(const bf16x8*)&Vs[0][kvo0 + 2048], pf0, o[2]);
      o[3] = mfma16(*(const bf16x8*)&Vs[0][kvo0 + 3072], pf0, o[3]);
      __builtin_amdgcn_s_setprio(0);
      const bf16x8 pf1 = *(const bf16x8*)pr1;
      __builtin_amdgcn_s_setprio(1);
      o[0] = mfma16(*(const bf16x8*)&Vs[0][kvo1 +    0], pf1, o[0]);
      o[1] = mfma16(*(const bf16x8*)&Vs[0][kvo1 + 1024], pf1, o[1]);
      o[2] = mfma16(*(const bf16x8*)&Vs[0][kvo1 + 2048], pf1, o[2]);
      o[3] = mfma16(*(const bf16x8*)&Vs[0][kvo1 + 3072], pf1, o[3]);
      __builtin_amdgcn_s_setprio(0);
    }
    // PV half 1 (keys kv0+64..kv0+127): reuse the same P region
    *(bf16x4*)pw0 = bf16x4{ (__bf16)s[4][0], (__bf16)s[4][1],
                            (__bf16)s[4][2], (__bf16)s[4][3] };
    *(bf16x4*)pw1 = bf16x4{ (__bf16)s[5][0], (__bf16)s[5][1],
                            (__bf16)s[5][2], (__bf16)s[5][3] };
    *(bf16x4*)pw2 = bf16x4{ (__bf16)s[6][0], (__bf16)s[6][1],
                            (__bf16)s[6][2], (__bf16)s[6][3] };
    *(bf16x4*)pw3 = bf16x4{ (__bf16)s[7][0], (__bf16)s[7][1],
                            (__bf16)s[7][2], (__bf16)s[7][3] };
    {
      const bf16x8 pf0 = *(const bf16x8*)pr0;
      __builtin_amdgcn_s_setprio(1);
      o[0] = mfma16(*(const bf16x8*)&Vs[1][kvo0 +    0], pf0, o[0]);
      o[1] = mfma16(*(const bf16x8*)&Vs[1][kvo0 + 1024], pf0, o[1]);
      o[2] = mfma16(*(const bf16x8*)&Vs[1][kvo0 + 2048], pf0, o[2]);
      o[3] = mfma16(*(const bf16x8*)&Vs[1][kvo0 + 3072], pf0, o[3]);
      __builtin_amdgcn_s_setprio(0);
      const bf16x8 pf1 = *(const bf16x8*)pr1;
      __builtin_amdgcn_s_setprio(1);
      o[0] = mfma16(*(const bf16x8*)&Vs[1][kvo1 +    0], pf1, o[0]);
      o[1] = mfma16(*(const bf16x8*)&Vs[1][kvo1 + 1024], pf1, o[1]);
      o[2] = mfma16(*(const bf16x8*)&Vs[1][kvo1 + 2048], pf1, o[2]);
      o[3] = mfma16(*(const bf16x8*)&Vs[1][kvo1 + 3072], pf1, o[3]);
      __builtin_amdgcn_s_setprio(0);
    }
    kpmb += 128;

    // single-buffer handoff: everyone done reading tile it -> stage it+1 ->
    // drain (compiler emits vmcnt(0) before s_barrier)
    if (it + 1 < niter) {
      __syncthreads();
      STAGE();
      __syncthreads();
    }
  }
#undef STAGE

  // row-reduce l across the 4 quads sharing q=l16 (once per block)
  float lt = l_run + __shfl_xor(l_run, 16);
  lt += __shfl_xor(lt, 32);

  // epilogue: normalize, O^T -> (q,d) via per-wave LDS, coalesced store
  const float inv_l = 1.0f / lt;
  {
    bf16x4 t0 = { (__bf16)(o[0][0] * inv_l), (__bf16)(o[0][1] * inv_l),
                  (__bf16)(o[0][2] * inv_l), (__bf16)(o[0][3] * inv_l) };
    bf16x4 t1 = { (__bf16)(o[1][0] * inv_l), (__bf16)(o[1][1] * inv_l),
                  (__bf16)(o[1][2] * inv_l), (__bf16)(o[1][3] * inv_l) };
    bf16x4 t2 = { (__bf16)(o[2][0] * inv_l), (__bf16)(o[2][1] * inv_l),
                  (__bf16)(o[2][2] * inv_l), (__bf16)(o[2][3] * inv_l) };
    bf16x4 t3 = { (__bf16)(o[3][0] * inv_l), (__bf16)(o[3][1] * inv_l),
                  (__bf16)(o[3][2] * inv_l), (__bf16)(o[3][3] * inv_l) };
    *(bf16x4*)pw0 = t0;
    *(bf16x4*)pw1 = t1;
    *(bf16x4*)pw2 = t2;
    *(bf16x4*)pw3 = t3;
  }
  const int h = bh & 7;
  #pragma unroll
  for (int ii = 0; ii < 2; ++ii) {
    const int qr = ii * 8 + (lane >> 3);
    const bf16x8 ovv = *(const bf16x8*)&Pw[qr * 64 + (((lane & 7) ^ (qr & 7)) << 3)];
    *(bf16x8*)(Oa + (((size_t)b * SEQ + q0 + wid * 16 + qr) * NHEAD + h) * HD +
               (lane & 7) * 8) = ovv;
  }
}

// ---------------------------------------------------------------------------
extern "C" void kernel_launch(void* const* d_in, const int* in_sizes, int n_in,
                              void* d_out, int out_size, void* d_ws, size_t ws_size,
                              hipStream_t stream) {
  (void)in_sizes; (void)n_in; (void)out_size; (void)ws_size;
  const float* query = (const float*)d_in[0];
  const float* key   = (const float*)d_in[1];
  const float* value = (const float*)d_in[2];
  const unsigned char* kpm = (const unsigned char*)d_in[3];
  // d_in[4] = attn_mask: deterministic causal tril -> applied analytically
  const float* Wq = (const float*)d_in[5];
  const float* bq = (const float*)d_in[6];
  const float* Wk = (const float*)d_in[7];
  const float* bk = (const float*)d_in[8];
  const float* Wv = (const float*)d_in[9];
  const float* bv = (const float*)d_in[10];
  const float* Wo = (const float*)d_in[11];
  const float* bo = (const float*)d_in[12];
  float* out = (float*)d_out;

  char* ws = (char*)d_ws;
  const size_t SZ = (size_t)MROWS * EMB * 2;  // 8 MiB per bf16 tensor
  __bf16* Qf = (__bf16*)(ws);
  __bf16* Kf = (__bf16*)(ws + SZ);
  __bf16* Vf = (__bf16*)(ws + 2 * SZ);
  __bf16* Qx = (__bf16*)(ws + 3 * SZ);
  __bf16* Kx = (__bf16*)(ws + 4 * SZ);
  __bf16* Vt = (__bf16*)(ws + 5 * SZ);
  __bf16* Wb = (__bf16*)(ws + 6 * SZ);        // 4 x 512KB bf16 weights
  float2* qtab = (float2*)(ws + 6 * SZ + 4 * (size_t)(EMB * EMB) * 2);
  float2* ktab = qtab + SEQ * 32;             // 512KB each
  __bf16* Oa = Qf;                            // alias: Qf dead after proj GEMM

  conv_kernel<<<dim3(2048, 5), dim3(256), 0, stream>>>(
      query, key, value, Wq, Wk, Wv, Wo, Qf, Kf, Vf, Wb, qtab, ktab);
  gemm_proj_kernel<<<dim3(4, 64, 3), dim3(256), 0, stream>>>(
      Qf, Kf, Vf, Wb, bq, bk, bv, qtab, ktab, Qx, Kx, Vt);
  flash_kernel<<<dim3(32, 32), dim3(256), 0, stream>>>(Qx, Kx, Vt, kpm, Oa);
  gemm_out_kernel<<<dim3(4, 64), dim3(256), 0, stream>>>(
      Oa, Wb + (size_t)3 * EMB * EMB, bo, out);
}